// Round 11
// baseline (216.716 us; speedup 1.0000x reference)
//
#include <hip/hip_runtime.h>

#define B_   8
#define C_   96
#define H_   160
#define W_   320
#define ND   9
#define NDD  81
#define TH   16
#define TW   16
#define KC   6                  // channels per chunk; wave w stages ch {cb+w, cb+3+w}
#define NCH  16
#define F2ROWS 18               // rows r0 .. r0+17
#define F2STRIDE 28             // 24 payload cols + 4 pad; 28*4 % 32 = 16 -> only free 2-way bank aliasing
#define F2PLANE (F2ROWS*F2STRIDE)   // 504 dw per channel
#define BUFW (KC*F2PLANE)           // 3024 dw = 12096 B
#define NBUF 3
#define LDSWORDS (NBUF*BUFW)        // 9072 dw = 36288 B -> 4 blocks/CU, regalloc target 3 w/EU (~170 reg budget)

#define AS1 __attribute__((address_space(1)))
#define AS3 __attribute__((address_space(3)))

__device__ __forceinline__ void gld16(const float* gp, float* lp) {
    // HBM/L2 -> LDS direct; LDS dest = wave-uniform base + lane*16
    __builtin_amdgcn_global_load_lds((const AS1 float*)gp,
                                     (AS3 float*)(unsigned long long)lp, 16, 0, 0);
}

__global__ __launch_bounds__(192, 2)
void corr_kernel(const float* __restrict__ f1g,
                 const float* __restrict__ f2g,
                 float* __restrict__ out)
{
    __shared__ float lds[LDSWORDS];

    const int tid  = threadIdx.x;
    const int wave = tid >> 6;          // dh-within-group AND staging channel offset
    const int lane = tid & 63;
    const int row  = lane >> 2;         // 0..15
    const int colb = (lane & 3) << 2;   // 0,4,8,12

    // XCD swizzle: 4800 = 8 XCDs x 600 (bijective). XCD owns batch b; the 3
    // dh-groups of a tile are dispatch-adjacent (halo/L2 reuse).
    const int bid  = blockIdx.x;
    const int ebid = (bid & 7) * 600 + (bid >> 3);
    const int b    = ebid / 600;
    const int t6   = ebid - b * 600;
    const int g    = t6 % 3;            // dh = 3g + wave
    const int tile = t6 / 3;
    const int by   = tile / 20, bx = tile - by * 20;
    const int x0 = bx * TW, y0 = by * TH;
    const int HWi  = H_ * W_;
    const int r0   = y0 + 3 * g - 4;    // first f2 halo row (global)

    const float* f1b = f1g + (size_t)b * C_ * HWi;
    const float* f2b = f2g + (size_t)b * C_ * HWi;

    // f1: direct global->reg, thread's own 4 px
    const float* f1p = f1b + (y0 + row) * W_ + x0 + colb;

    // f2 staging lane maps, stride-28 rows: segment s -> lds dw 4s,
    // r = s/7, c = 4*(s%7). c==24 is the pad column (never staged/read).
    // part0: s = lane; part1: s = 64+lane (s < 126).
    // Halo x-offset (4) == segment width -> segment fully in or out: gx in [0, W-4].
    int so0, so1; bool p0, p1;
    {
        int s, r, c, gy, gx;
        s = lane;      r = s / 7; c = (s - 7 * r) << 2;
        gy = r0 + r;   gx = x0 - 4 + c;
        p0 = (c < 24) & (gy >= 0) & (gy < H_) & (gx >= 0) & (gx <= W_ - 4);
        so0 = gy * W_ + gx;
        s = 64 + lane; r = s / 7; c = (s - 7 * r) << 2;
        gy = r0 + r;   gx = x0 - 4 + c;
        p1 = (s < 126) & (c < 24) & (gy >= 0) & (gy < H_) & (gx >= 0) & (gx <= W_ - 4);
        so1 = gy * W_ + gx;
    }

    // compute-side read base: f2 lds row = out_row + wave
    const int o0 = (row + wave) * F2STRIDE + colb;

    // stage chunk cb..cb+5: wave w stages channels cb+w and cb+3+w
    // (exactly 4 gld16 issued per wave: predicates never kill all 64 lanes)
    auto stage = [&](int cb, int bufb) {
#pragma unroll
        for (int j = 0; j < 2; ++j) {
            const int ch = 3 * j + wave;
            const int co = (cb + ch) * HWi;
            float* l = &lds[bufb + ch * F2PLANE];
            if (p0) gld16(f2b + co + so0, l);
            if (p1) gld16(f2b + co + so1, l + 256);
        }
    };

    float4 acc0, acc1, acc2, acc3, acc4, acc5, acc6, acc7, acc8;
    acc0 = acc1 = acc2 = acc3 = acc4 = acc5 = acc6 = acc7 = acc8 = make_float4(0.f, 0.f, 0.f, 0.f);
    float4 P0, P1, P2, P3, P4, P5;

#define F1LOAD(cb) {                                         \
        P0 = *(const float4*)(f1p + (cb) * HWi);             \
        P1 = *(const float4*)(f1p + ((cb) + 1) * HWi);       \
        P2 = *(const float4*)(f1p + ((cb) + 2) * HWi);       \
        P3 = *(const float4*)(f1p + ((cb) + 3) * HWi);       \
        P4 = *(const float4*)(f1p + ((cb) + 4) * HWi);       \
        P5 = *(const float4*)(f1p + ((cb) + 5) * HWi); }

#define STEPD(A, P, e0, e1, e2, e3)                          \
        A.x = fmaf(P.x, e0, A.x);                            \
        A.y = fmaf(P.y, e1, A.y);                            \
        A.z = fmaf(P.z, e2, A.z);                            \
        A.w = fmaf(P.w, e3, A.w);

#define COMPC(c, RB, P) {                                                         \
        const float4 q0 = *(const float4*)&lds[(RB) + c * F2PLANE + o0];          \
        const float4 q1 = *(const float4*)&lds[(RB) + c * F2PLANE + o0 + 4];      \
        const float4 q2 = *(const float4*)&lds[(RB) + c * F2PLANE + o0 + 8];      \
        STEPD(acc0, P, q0.x, q0.y, q0.z, q0.w)                                    \
        STEPD(acc1, P, q0.y, q0.z, q0.w, q1.x)                                    \
        STEPD(acc2, P, q0.z, q0.w, q1.x, q1.y)                                    \
        STEPD(acc3, P, q0.w, q1.x, q1.y, q1.z)                                    \
        STEPD(acc4, P, q1.x, q1.y, q1.z, q1.w)                                    \
        STEPD(acc5, P, q1.y, q1.z, q1.w, q2.x)                                    \
        STEPD(acc6, P, q1.z, q1.w, q2.x, q2.y)                                    \
        STEPD(acc7, P, q1.w, q2.x, q2.y, q2.z)                                    \
        STEPD(acc8, P, q2.x, q2.y, q2.z, q2.w)                                    \
    }
#define CHUNK(RB) COMPC(0,RB,P0) COMPC(1,RB,P1) COMPC(2,RB,P2) \
                  COMPC(3,RB,P3) COMPC(4,RB,P4) COMPC(5,RB,P5)

    // one-time zero (pad cols / OOB slots are never DMA'd; payload rewritten
    // every chunk -> zeros persist)
    for (int t = tid; t < LDSWORDS; t += 192) lds[t] = 0.f;
    __syncthreads();

    // prologue: prefetch chunks 0,1 (depth 2)
    stage(0, 0);
    stage(KC, BUFW);

#pragma unroll 1
    for (int k = 0; k < NCH; ++k) {
        // counted wait: retire own S(k) (4 DMAs), keep S(k+1)'s 4 in flight
        if (k < NCH - 1) { asm volatile("s_waitcnt vmcnt(4)" ::: "memory"); }
        else             { asm volatile("s_waitcnt vmcnt(0)" ::: "memory"); }
        __builtin_amdgcn_s_barrier();          // all waves' chunk-k data in LDS
        __builtin_amdgcn_sched_barrier(0);     // no ds_read hoists above barrier
        F1LOAD(KC * k)                          // f1 first: P-use waits won't drain DMAs
        __builtin_amdgcn_sched_barrier(0);
        if (k + 2 < NCH) stage(KC * (k + 2), ((k + 2) % NBUF) * BUFW);
        __builtin_amdgcn_sched_barrier(0);
        const int rb_ = (k % NBUF) * BUFW;
        CHUNK(rb_)
    }

    // ---- epilogue: dh = 3g + wave; out[b, dh*9+d, y0+row, x0+colb..+3] ----
    const int dh = 3 * g + wave;
    const int gy = y0 + row;
    const int gx = x0 + colb;
#define STORED(d) {                                                                 \
        float* op_ = out + (size_t)((b * NDD + dh * ND + d) * H_ + gy) * W_ + gx;   \
        *(float4*)op_ = acc##d; }
    STORED(0) STORED(1) STORED(2) STORED(3) STORED(4)
    STORED(5) STORED(6) STORED(7) STORED(8)
}

extern "C" void kernel_launch(void* const* d_in, const int* in_sizes, int n_in,
                              void* d_out, int out_size, void* d_ws, size_t ws_size,
                              hipStream_t stream)
{
    const float* f1 = (const float*)d_in[0];
    const float* f2 = (const float*)d_in[1];
    float* out = (float*)d_out;
    corr_kernel<<<dim3(4800), 192, 0, stream>>>(f1, f2, out);
}

// Round 12
// 197.105 us; speedup vs baseline: 1.0995x; 1.0995x over previous
//
#include <hip/hip_runtime.h>

#define B_   8
#define C_   96
#define H_   160
#define W_   320
#define ND   9
#define NDD  81
#define TH   16
#define TW   32                 // 8 px/thread: 64 lanes = 16 rows x 4 col-groups of 8
#define KC   4                  // channels per chunk
#define NCH  24
#define F2ROWS 18               // rows r0 .. r0+17
#define F2STRIDE 40             // 40 halo cols (32 + 2*4), exact, no pad
#define F2PLANE (F2ROWS*F2STRIDE)   // 720 dw per channel = 180 16B segments
#define BUFW (KC*F2PLANE)           // 2880 dw = 11520 B
#define NBUF 3
#define LDSWORDS (NBUF*BUFW)        // 8640 dw = 34560 B -> 4 blocks/CU -> regalloc
                                    // target 3 waves/EU -> ~170-reg budget (no spill at ~140 demand)

#define AS1 __attribute__((address_space(1)))
#define AS3 __attribute__((address_space(3)))

__device__ __forceinline__ void gld16(const float* gp, float* lp) {
    // HBM/L2 -> LDS direct; LDS dest = wave-uniform base + lane*16
    __builtin_amdgcn_global_load_lds((const AS1 float*)gp,
                                     (AS3 float*)(unsigned long long)lp, 16, 0, 0);
}

__global__ __launch_bounds__(192, 2)
void corr_kernel(const float* __restrict__ f1g,
                 const float* __restrict__ f2g,
                 float* __restrict__ out)
{
    __shared__ float lds[LDSWORDS];

    const int tid  = threadIdx.x;
    const int wave = tid >> 6;          // dh-within-group AND staging part index
    const int lane = tid & 63;
    const int row  = lane >> 2;         // 0..15
    const int colb = (lane & 3) << 3;   // 0,8,16,24: 8 px per thread

    // XCD swizzle: 2400 = 8 XCDs x 300 (bijective). XCD owns batch b; the 3
    // dh-groups of a tile are dispatch-adjacent (halo/L2 reuse).
    const int bid  = blockIdx.x;
    const int ebid = (bid & 7) * 300 + (bid >> 3);
    const int b    = ebid / 300;
    const int t3   = ebid - b * 300;
    const int g    = t3 % 3;            // dh = 3g + wave
    const int tile = t3 / 3;            // 0..99
    const int by   = tile / 10, bx = tile - by * 10;
    const int x0 = bx * TW, y0 = by * TH;
    const int HWi  = H_ * W_;
    const int r0   = y0 + 3 * g - 4;    // first f2 halo row (global)

    const float* f1b = f1g + (size_t)b * C_ * HWi;
    const float* f2b = f2g + (size_t)b * C_ * HWi;

    // f1: direct global->reg, thread's own 8 px
    const float* f1p = f1b + (y0 + row) * W_ + x0 + colb;

    // f2 staging: plane = 180 16B segments; seg s -> lds dw 4s, r = s/10,
    // c4 = s%10 (halo col 4*c4). Wave w stages part w: s = 64w + lane
    // (part 2 active for lane<52). Halo x-offset (4) == segment width ->
    // a segment is fully in or fully out: gx in [0, W-4] exact.
    int soW; bool ppW;
    {
        const int s  = (wave << 6) + lane;
        const int r  = s / 10, c4 = s - 10 * r;
        const int gy = r0 + r, gx = x0 - 4 + (c4 << 2);
        ppW = (s < 180) & (gy >= 0) & (gy < H_) & (gx >= 0) & (gx <= W_ - 4);
        soW = gy * W_ + gx;
    }
    const int partoff = wave << 8;      // lds dw offset of this wave's part (0,256,512)

    // compute-side read base: f2 lds row = out_row + wave, cols colb..colb+15
    const int o0 = (row + wave) * F2STRIDE + colb;

    // stage chunk cb..cb+3: wave w issues exactly 4 predicated gld16
    auto stage = [&](int cb, int bufb) {
#pragma unroll
        for (int c = 0; c < KC; ++c) {
            if (ppW) gld16(f2b + (cb + c) * HWi + soW,
                           &lds[bufb + c * F2PLANE + partoff]);
        }
    };

    // ---- accumulators: 9 offsets x 8 px (A = px0-3, B = px4-7) ----
    float4 accA0, accA1, accA2, accA3, accA4, accA5, accA6, accA7, accA8;
    float4 accB0, accB1, accB2, accB3, accB4, accB5, accB6, accB7, accB8;
    accA0=accA1=accA2=accA3=accA4=accA5=accA6=accA7=accA8 = make_float4(0.f,0.f,0.f,0.f);
    accB0=accB1=accB2=accB3=accB4=accB5=accB6=accB7=accB8 = make_float4(0.f,0.f,0.f,0.f);
    float4 PA0, PA1, PA2, PA3, PB0, PB1, PB2, PB3;

#define F1LOAD(cb) {                                              \
        PA0 = *(const float4*)(f1p + (cb) * HWi);                 \
        PB0 = *(const float4*)(f1p + (cb) * HWi + 4);             \
        PA1 = *(const float4*)(f1p + ((cb)+1) * HWi);             \
        PB1 = *(const float4*)(f1p + ((cb)+1) * HWi + 4);         \
        PA2 = *(const float4*)(f1p + ((cb)+2) * HWi);             \
        PB2 = *(const float4*)(f1p + ((cb)+2) * HWi + 4);         \
        PA3 = *(const float4*)(f1p + ((cb)+3) * HWi);             \
        PB3 = *(const float4*)(f1p + ((cb)+3) * HWi + 4); }

#define STEPD(A, P, e0, e1, e2, e3)                          \
        A.x = fmaf(P.x, e0, A.x);                            \
        A.y = fmaf(P.y, e1, A.y);                            \
        A.z = fmaf(P.z, e2, A.z);                            \
        A.w = fmaf(P.w, e3, A.w);

    // window w[j] = f2 halo col (colb + j); acc_d[px p] += P[p] * w[p+d]
#define COMPC(c, RB, PA, PB) {                                                    \
        const float4 q0 = *(const float4*)&lds[(RB) + c * F2PLANE + o0];          \
        const float4 q1 = *(const float4*)&lds[(RB) + c * F2PLANE + o0 + 4];      \
        const float4 q2 = *(const float4*)&lds[(RB) + c * F2PLANE + o0 + 8];      \
        const float4 q3 = *(const float4*)&lds[(RB) + c * F2PLANE + o0 + 12];     \
        const float w[16] = {q0.x,q0.y,q0.z,q0.w,q1.x,q1.y,q1.z,q1.w,            \
                             q2.x,q2.y,q2.z,q2.w,q3.x,q3.y,q3.z,q3.w};           \
        STEPD(accA0, PA, w[0], w[1], w[2], w[3])                                  \
        STEPD(accB0, PB, w[4], w[5], w[6], w[7])                                  \
        STEPD(accA1, PA, w[1], w[2], w[3], w[4])                                  \
        STEPD(accB1, PB, w[5], w[6], w[7], w[8])                                  \
        STEPD(accA2, PA, w[2], w[3], w[4], w[5])                                  \
        STEPD(accB2, PB, w[6], w[7], w[8], w[9])                                  \
        STEPD(accA3, PA, w[3], w[4], w[5], w[6])                                  \
        STEPD(accB3, PB, w[7], w[8], w[9], w[10])                                 \
        STEPD(accA4, PA, w[4], w[5], w[6], w[7])                                  \
        STEPD(accB4, PB, w[8], w[9], w[10], w[11])                                \
        STEPD(accA5, PA, w[5], w[6], w[7], w[8])                                  \
        STEPD(accB5, PB, w[9], w[10], w[11], w[12])                               \
        STEPD(accA6, PA, w[6], w[7], w[8], w[9])                                  \
        STEPD(accB6, PB, w[10], w[11], w[12], w[13])                              \
        STEPD(accA7, PA, w[7], w[8], w[9], w[10])                                 \
        STEPD(accB7, PB, w[11], w[12], w[13], w[14])                              \
        STEPD(accA8, PA, w[8], w[9], w[10], w[11])                                \
        STEPD(accB8, PB, w[12], w[13], w[14], w[15])                              \
    }
#define CHUNK(RB) COMPC(0,RB,PA0,PB0) COMPC(1,RB,PA1,PB1) \
                  COMPC(2,RB,PA2,PB2) COMPC(3,RB,PA3,PB3)

    // one-time zero (OOB slots never DMA'd; payload rewritten every chunk)
    for (int t = tid; t < LDSWORDS; t += 192) lds[t] = 0.f;
    __syncthreads();

    // prologue: prefetch chunks 0,1 (depth 2)
    stage(0, 0);
    stage(KC, BUFW);

#pragma unroll 1
    for (int k = 0; k < NCH; ++k) {
        // own S(k) already forced by prev iter's P-wait; explicit wait is
        // cheap insurance (and required for k=0)
        if (k < NCH - 1) { asm volatile("s_waitcnt vmcnt(4)" ::: "memory"); }
        else             { asm volatile("s_waitcnt vmcnt(0)" ::: "memory"); }
        __builtin_amdgcn_s_barrier();          // all waves' chunk-k data in LDS
        __builtin_amdgcn_sched_barrier(0);
        F1LOAD(KC * k)                          // f1 BEFORE stage: P-wait leaves S(k+2) flying
        __builtin_amdgcn_sched_barrier(0);
        if (k + 2 < NCH) stage(KC * (k + 2), ((k + 2) % NBUF) * BUFW);
        __builtin_amdgcn_sched_barrier(0);
        const int rb_ = (k % NBUF) * BUFW;
        CHUNK(rb_)
    }

    // ---- epilogue: dh = 3g + wave; out[b, dh*9+d, y0+row, x0+colb..+7] ----
    const int dh = 3 * g + wave;
    const int gy = y0 + row;
    const int gx = x0 + colb;
#define STORED(d) {                                                                 \
        float* op_ = out + (size_t)((b * NDD + dh * ND + d) * H_ + gy) * W_ + gx;   \
        *(float4*)op_ = accA##d;                                                    \
        *(float4*)(op_ + 4) = accB##d; }
    STORED(0) STORED(1) STORED(2) STORED(3) STORED(4)
    STORED(5) STORED(6) STORED(7) STORED(8)
}

extern "C" void kernel_launch(void* const* d_in, const int* in_sizes, int n_in,
                              void* d_out, int out_size, void* d_ws, size_t ws_size,
                              hipStream_t stream)
{
    const float* f1 = (const float*)d_in[0];
    const float* f2 = (const float*)d_in[1];
    float* out = (float*)d_out;
    corr_kernel<<<dim3(2400), 192, 0, stream>>>(f1, f2, out);
}